// Round 1
// baseline (437.896 us; speedup 1.0000x reference)
//
#include <hip/hip_runtime.h>

#define NN 10000
#define NE 640000
#define IN_DIM 128
#define HID_DIM 512
#define OUT_DIM 512

__global__ void zero_int_kernel(int* __restrict__ p, int n) {
    int i = blockIdx.x * blockDim.x + threadIdx.x;
    if (i < n) p[i] = 0;
}

__global__ void degree_kernel(const int* __restrict__ src, const int* __restrict__ dst,
                              int* __restrict__ deg_out, int* __restrict__ deg_in, int E) {
    int e = blockIdx.x * blockDim.x + threadIdx.x;
    if (e < E) {
        atomicAdd(&deg_out[src[e]], 1);
        atomicAdd(&deg_in[dst[e]], 1);
    }
}

__global__ void norm_kernel(const int* __restrict__ deg_out, const int* __restrict__ deg_in,
                            float* __restrict__ norm_src, float* __restrict__ norm_dst, int n) {
    int i = blockIdx.x * blockDim.x + threadIdx.x;
    if (i < n) {
        norm_src[i] = rsqrtf(fmaxf((float)deg_out[i], 1.0f));
        norm_dst[i] = rsqrtf(fmaxf((float)deg_in[i], 1.0f));
    }
}

// Single-block exclusive scan of deg_in[0..n) -> row_off[0..n] (row_off[n]=total), cursor=row_off copy.
// 1024 threads, each handles 10 contiguous elements (10240 >= n).
__global__ __launch_bounds__(1024) void scan_kernel(const int* __restrict__ deg,
                                                    int* __restrict__ row_off,
                                                    int* __restrict__ cursor, int n) {
    const int PER = 10;
    __shared__ int lds[1024];
    int t = threadIdx.x;
    int base = t * PER;
    int local[PER];
    int s = 0;
#pragma unroll
    for (int i = 0; i < PER; i++) {
        int idx = base + i;
        int v = (idx < n) ? deg[idx] : 0;
        local[i] = s;   // exclusive prefix within segment
        s += v;
    }
    lds[t] = s;
    __syncthreads();
    // Hillis-Steele inclusive scan over 1024 segment sums
    for (int off = 1; off < 1024; off <<= 1) {
        int x = (t >= off) ? lds[t - off] : 0;
        __syncthreads();
        lds[t] += x;
        __syncthreads();
    }
    int excl = lds[t] - s;  // exclusive prefix of this segment
#pragma unroll
    for (int i = 0; i < PER; i++) {
        int idx = base + i;
        if (idx < n) {
            int e = excl + local[i];
            row_off[idx] = e;
            cursor[idx] = e;
        }
    }
    if (t == 1023) row_off[n] = lds[1023];
}

__global__ void csr_fill_kernel(const int* __restrict__ src, const int* __restrict__ dst,
                                int* __restrict__ cursor, int* __restrict__ csr_src, int E) {
    int e = blockIdx.x * blockDim.x + threadIdx.x;
    if (e < E) {
        int p = atomicAdd(&cursor[dst[e]], 1);
        csr_src[p] = src[e];
    }
}

// One block per node, 128 threads (one per feature dim). agg = norm_dst[n] * sum_e feat[src_e]*norm_src[src_e]
__global__ __launch_bounds__(128) void agg1_kernel(const float* __restrict__ feat,
                                                   const int* __restrict__ row_off,
                                                   const int* __restrict__ csr_src,
                                                   const float* __restrict__ norm_src,
                                                   const float* __restrict__ norm_dst,
                                                   float* __restrict__ agg) {
    int node = blockIdx.x;
    int t = threadIdx.x;
    int beg = row_off[node], end = row_off[node + 1];
    float s = 0.0f;
    for (int i = beg; i < end; i++) {
        int u = csr_src[i];
        s += feat[(size_t)u * IN_DIM + t] * norm_src[u];
    }
    agg[(size_t)node * IN_DIM + t] = s * norm_dst[node];
}

// One block per node, 256 threads, 2 dims each (512-dim rows)
__global__ __launch_bounds__(256) void agg2_kernel(const float* __restrict__ h,
                                                   const int* __restrict__ row_off,
                                                   const int* __restrict__ csr_src,
                                                   const float* __restrict__ norm_src,
                                                   const float* __restrict__ norm_dst,
                                                   float* __restrict__ agg) {
    int node = blockIdx.x;
    int t = threadIdx.x;
    int beg = row_off[node], end = row_off[node + 1];
    float s0 = 0.0f, s1 = 0.0f;
    for (int i = beg; i < end; i++) {
        int u = csr_src[i];
        float w = norm_src[u];
        const float* row = h + (size_t)u * HID_DIM;
        s0 += row[t] * w;
        s1 += row[t + 256] * w;
    }
    float nd = norm_dst[node];
    agg[(size_t)node * HID_DIM + t] = s0 * nd;
    agg[(size_t)node * HID_DIM + t + 256] = s1 * nd;
}

// fp32 tiled GEMM: C[M][N] = A[M][K] @ W[K][N] + bias (+optional relu)
// 64x64 tile, BK=32, 256 threads, 4x4 microtile.
template <int RELU>
__global__ __launch_bounds__(256) void gemm_kernel(const float* __restrict__ A,
                                                   const float* __restrict__ W,
                                                   const float* __restrict__ bias,
                                                   float* __restrict__ C,
                                                   int M, int K, int N) {
    const int BM = 64, BN = 64, BK = 32;
    __shared__ __align__(16) float As[BK][BM + 4];  // k-major (transposed)
    __shared__ __align__(16) float Bs[BK][BN + 4];
    int tid = threadIdx.x;
    int bm = blockIdx.x * BM;
    int bn = blockIdx.y * BN;
    int tm = (tid >> 4) * 4;   // 0..60
    int tn = (tid & 15) * 4;   // 0..60

    float acc[4][4] = {};

    for (int k0 = 0; k0 < K; k0 += BK) {
        // Load A tile: 64 rows x 32 k = 512 float4 (along k)
#pragma unroll
        for (int u = 0; u < 2; u++) {
            int l = u * 256 + tid;
            int r = l >> 3;      // row 0..63
            int kq = l & 7;      // float4 index along k
            float4 v;
            int gm = bm + r;
            if (gm < M) {
                v = *(const float4*)&A[(size_t)gm * K + k0 + kq * 4];
            } else {
                v = make_float4(0.f, 0.f, 0.f, 0.f);
            }
            As[kq * 4 + 0][r] = v.x;
            As[kq * 4 + 1][r] = v.y;
            As[kq * 4 + 2][r] = v.z;
            As[kq * 4 + 3][r] = v.w;
        }
        // Load B tile: 32 k-rows x 64 n = 512 float4
#pragma unroll
        for (int u = 0; u < 2; u++) {
            int l = u * 256 + tid;
            int kk = l >> 4;     // 0..31
            int nq = l & 15;     // float4 along n
            float4 v = *(const float4*)&W[(size_t)(k0 + kk) * N + bn + nq * 4];
            *(float4*)&Bs[kk][nq * 4] = v;
        }
        __syncthreads();
#pragma unroll
        for (int kk = 0; kk < BK; kk++) {
            float av[4], bv[4];
            *(float4*)av = *(const float4*)&As[kk][tm];
            *(float4*)bv = *(const float4*)&Bs[kk][tn];
#pragma unroll
            for (int i = 0; i < 4; i++)
#pragma unroll
                for (int j = 0; j < 4; j++) acc[i][j] += av[i] * bv[j];
        }
        __syncthreads();
    }

#pragma unroll
    for (int i = 0; i < 4; i++) {
        int gm = bm + tm + i;
        if (gm < M) {
            float4 v;
            v.x = acc[i][0] + bias[bn + tn + 0];
            v.y = acc[i][1] + bias[bn + tn + 1];
            v.z = acc[i][2] + bias[bn + tn + 2];
            v.w = acc[i][3] + bias[bn + tn + 3];
            if (RELU) {
                v.x = fmaxf(v.x, 0.f);
                v.y = fmaxf(v.y, 0.f);
                v.z = fmaxf(v.z, 0.f);
                v.w = fmaxf(v.w, 0.f);
            }
            *(float4*)&C[(size_t)gm * N + bn + tn] = v;
        }
    }
}

extern "C" void kernel_launch(void* const* d_in, const int* in_sizes, int n_in,
                              void* d_out, int out_size, void* d_ws, size_t ws_size,
                              hipStream_t stream) {
    const float* feat = (const float*)d_in[0];
    const int* ei = (const int*)d_in[1];
    const float* W1 = (const float*)d_in[2];
    const float* b1 = (const float*)d_in[3];
    const float* W2 = (const float*)d_in[4];
    const float* b2 = (const float*)d_in[5];
    float* out = (float*)d_out;

    const int* src = ei;
    const int* dst = ei + NE;

    // Workspace layout (256B-aligned chunks)
    char* ws = (char*)d_ws;
    size_t off = 0;
    auto alloc = [&](size_t bytes) -> void* {
        void* p = ws + off;
        off += (bytes + 255) & ~(size_t)255;
        return p;
    };
    int* deg = (int*)alloc(2 * 10240 * sizeof(int));   // deg_out | deg_in
    int* deg_out = deg;
    int* deg_in = deg + 10240;
    int* row_off = (int*)alloc((NN + 16) * sizeof(int));
    int* cursor = (int*)alloc(NN * sizeof(int));
    float* norm_src = (float*)alloc(NN * sizeof(float));
    float* norm_dst = (float*)alloc(NN * sizeof(float));
    int* csr_src = (int*)alloc(NE * sizeof(int));
    float* agg1 = (float*)alloc((size_t)NN * IN_DIM * sizeof(float));
    float* agg2 = (float*)alloc((size_t)NN * HID_DIM * sizeof(float));
    float* h = out;  // borrow d_out as scratch for hidden layer

    zero_int_kernel<<<(2 * 10240 + 255) / 256, 256, 0, stream>>>(deg, 2 * 10240);
    degree_kernel<<<(NE + 255) / 256, 256, 0, stream>>>(src, dst, deg_out, deg_in, NE);
    scan_kernel<<<1, 1024, 0, stream>>>(deg_in, row_off, cursor, NN);
    norm_kernel<<<(NN + 255) / 256, 256, 0, stream>>>(deg_out, deg_in, norm_src, norm_dst, NN);
    csr_fill_kernel<<<(NE + 255) / 256, 256, 0, stream>>>(src, dst, cursor, csr_src, NE);

    // Layer 1: aggregate (128-dim) then GEMM+bias+relu -> h (in d_out)
    agg1_kernel<<<NN, 128, 0, stream>>>(feat, row_off, csr_src, norm_src, norm_dst, agg1);
    {
        dim3 grid((NN + 63) / 64, HID_DIM / 64);
        gemm_kernel<1><<<grid, 256, 0, stream>>>(agg1, W1, b1, h, NN, IN_DIM, HID_DIM);
    }
    // Layer 2: aggregate (512-dim) then GEMM+bias -> out
    agg2_kernel<<<NN, 256, 0, stream>>>(h, row_off, csr_src, norm_src, norm_dst, agg2);
    {
        dim3 grid((NN + 63) / 64, OUT_DIM / 64);
        gemm_kernel<0><<<grid, 256, 0, stream>>>(agg2, W2, b2, out, NN, HID_DIM, OUT_DIM);
    }
}

// Round 2
// 249.653 us; speedup vs baseline: 1.7540x; 1.7540x over previous
//
#include <hip/hip_runtime.h>

#define NN 10000
#define NE 640000
#define IN_DIM 128
#define HID_DIM 512
#define OUT_DIM 512

typedef __attribute__((ext_vector_type(8))) short short8;
typedef __attribute__((ext_vector_type(4))) float f32x4;

__device__ __forceinline__ ushort f2b(float f) {
    union { float f; uint i; } c; c.f = f;
    uint x = c.i;
    uint r = (x + 0x7fffu + ((x >> 16) & 1u)) >> 16;
    return (ushort)r;
}
__device__ __forceinline__ float blo(uint a) {
    union { uint i; float f; } c; c.i = a << 16; return c.f;
}
__device__ __forceinline__ float bhi(uint a) {
    union { uint i; float f; } c; c.i = a & 0xffff0000u; return c.f;
}

__global__ void zero_int_kernel(int* __restrict__ p, int n) {
    int i = blockIdx.x * blockDim.x + threadIdx.x;
    if (i < n) p[i] = 0;
}

__global__ void degree_kernel(const int* __restrict__ src, const int* __restrict__ dst,
                              int* __restrict__ deg_out, int* __restrict__ deg_in, int E) {
    int e = blockIdx.x * blockDim.x + threadIdx.x;
    if (e < E) {
        atomicAdd(&deg_out[src[e]], 1);
        atomicAdd(&deg_in[dst[e]], 1);
    }
}

__global__ void norm_kernel(const int* __restrict__ deg_out, const int* __restrict__ deg_in,
                            float* __restrict__ norm_src, float* __restrict__ norm_dst, int n) {
    int i = blockIdx.x * blockDim.x + threadIdx.x;
    if (i < n) {
        norm_src[i] = rsqrtf(fmaxf((float)deg_out[i], 1.0f));
        norm_dst[i] = rsqrtf(fmaxf((float)deg_in[i], 1.0f));
    }
}

// Single-block exclusive scan of deg[0..n) -> row_off[0..n], cursor copy.
__global__ __launch_bounds__(1024) void scan_kernel(const int* __restrict__ deg,
                                                    int* __restrict__ row_off,
                                                    int* __restrict__ cursor, int n) {
    const int PER = 10;
    __shared__ int lds[1024];
    int t = threadIdx.x;
    int base = t * PER;
    int local[PER];
    int s = 0;
#pragma unroll
    for (int i = 0; i < PER; i++) {
        int idx = base + i;
        int v = (idx < n) ? deg[idx] : 0;
        local[i] = s;
        s += v;
    }
    lds[t] = s;
    __syncthreads();
    for (int off = 1; off < 1024; off <<= 1) {
        int x = (t >= off) ? lds[t - off] : 0;
        __syncthreads();
        lds[t] += x;
        __syncthreads();
    }
    int excl = lds[t] - s;
#pragma unroll
    for (int i = 0; i < PER; i++) {
        int idx = base + i;
        if (idx < n) {
            int e = excl + local[i];
            row_off[idx] = e;
            cursor[idx] = e;
        }
    }
    if (t == 1023) row_off[n] = lds[1023];
}

__global__ void csr_fill_kernel(const int* __restrict__ src, const int* __restrict__ dst,
                                int* __restrict__ cursor, int* __restrict__ csr_src, int E) {
    int e = blockIdx.x * blockDim.x + threadIdx.x;
    if (e < E) {
        int p = atomicAdd(&cursor[dst[e]], 1);
        csr_src[p] = src[e];
    }
}

// featb[u][d] = bf16(feat[u][d] * norm_src[u])
__global__ void featconv_kernel(const float* __restrict__ feat,
                                const float* __restrict__ norm_src,
                                ushort* __restrict__ featb) {
    int i = blockIdx.x * blockDim.x + threadIdx.x;  // float4 index
    if (i < NN * IN_DIM / 4) {
        float4 v = ((const float4*)feat)[i];
        float s = norm_src[i >> 5];  // (i*4)/128
        ushort4 o;
        o.x = f2b(v.x * s); o.y = f2b(v.y * s); o.z = f2b(v.z * s); o.w = f2b(v.w * s);
        ((ushort4*)featb)[i] = o;
    }
}

// Wt[n][k] = bf16(W[k][n]); 32x32 LDS tile transpose, 256 threads
__global__ __launch_bounds__(256) void transpose_bf16_kernel(const float* __restrict__ W,
                                                             ushort* __restrict__ Wt,
                                                             int K, int N) {
    __shared__ float t[32][33];
    int k0 = blockIdx.x * 32, n0 = blockIdx.y * 32;
    int tx = threadIdx.x & 31, ty = threadIdx.x >> 5;  // ty 0..7
#pragma unroll
    for (int r = 0; r < 32; r += 8)
        t[ty + r][tx] = W[(size_t)(k0 + ty + r) * N + n0 + tx];
    __syncthreads();
#pragma unroll
    for (int r = 0; r < 32; r += 8)
        Wt[(size_t)(n0 + ty + r) * K + k0 + tx] = f2b(t[tx][ty + r]);
}

// One wave per node. fb rows: 64 uints (128 bf16, pre-scaled by norm_src).
__global__ __launch_bounds__(64) void agg1_kernel(const uint* __restrict__ fb,
                                                  const int* __restrict__ row_off,
                                                  const int* __restrict__ csr_src,
                                                  const float* __restrict__ norm_dst,
                                                  uint* __restrict__ aggb) {
    int node = blockIdx.x;
    int lane = threadIdx.x;
    int beg = row_off[node], end = row_off[node + 1];
    float s0 = 0.f, s1 = 0.f;
    int i = beg;
    for (; i + 3 < end; i += 4) {
        int u0 = csr_src[i], u1 = csr_src[i + 1], u2 = csr_src[i + 2], u3 = csr_src[i + 3];
        uint a0 = fb[u0 * 64 + lane];
        uint a1 = fb[u1 * 64 + lane];
        uint a2 = fb[u2 * 64 + lane];
        uint a3 = fb[u3 * 64 + lane];
        s0 += blo(a0); s1 += bhi(a0);
        s0 += blo(a1); s1 += bhi(a1);
        s0 += blo(a2); s1 += bhi(a2);
        s0 += blo(a3); s1 += bhi(a3);
    }
    for (; i < end; i++) {
        uint a = fb[csr_src[i] * 64 + lane];
        s0 += blo(a); s1 += bhi(a);
    }
    float nd = norm_dst[node];
    aggb[node * 64 + lane] = (uint)f2b(s0 * nd) | ((uint)f2b(s1 * nd) << 16);
}

// One block (256 thr) per node. hb rows: 256 uints (512 bf16, pre-scaled by norm_src).
__global__ __launch_bounds__(256) void agg2_kernel(const uint* __restrict__ hb,
                                                   const int* __restrict__ row_off,
                                                   const int* __restrict__ csr_src,
                                                   const float* __restrict__ norm_dst,
                                                   uint* __restrict__ aggb) {
    int node = blockIdx.x;
    int t = threadIdx.x;
    int beg = row_off[node], end = row_off[node + 1];
    float s0 = 0.f, s1 = 0.f;
    int i = beg;
    for (; i + 3 < end; i += 4) {
        int u0 = csr_src[i], u1 = csr_src[i + 1], u2 = csr_src[i + 2], u3 = csr_src[i + 3];
        uint a0 = hb[u0 * 256 + t];
        uint a1 = hb[u1 * 256 + t];
        uint a2 = hb[u2 * 256 + t];
        uint a3 = hb[u3 * 256 + t];
        s0 += blo(a0); s1 += bhi(a0);
        s0 += blo(a1); s1 += bhi(a1);
        s0 += blo(a2); s1 += bhi(a2);
        s0 += blo(a3); s1 += bhi(a3);
    }
    for (; i < end; i++) {
        uint a = hb[csr_src[i] * 256 + t];
        s0 += blo(a); s1 += bhi(a);
    }
    float nd = norm_dst[node];
    aggb[node * 256 + t] = (uint)f2b(s0 * nd) | ((uint)f2b(s1 * nd) << 16);
}

// bf16 MFMA GEMM: C[M][N] = A[M][K] @ Bt[N][K]^T (+bias, epilogue variants)
// BM=128 BN=64 BK=32, 256 threads = 4 waves (2x2), fragment-ordered LDS.
// EPI 0: fp32 out = acc + bias.   EPI 1: bf16 out = relu(acc+bias) * scale[row].
template <int EPI>
__global__ __launch_bounds__(256) void gemm_bf16_kernel(const ushort* __restrict__ A,
                                                        const ushort* __restrict__ Bt,
                                                        const float* __restrict__ bias,
                                                        const float* __restrict__ scale,
                                                        void* __restrict__ Cout,
                                                        int M, int K, int N) {
    const int BM = 128, BN = 64, BK = 32;
    __shared__ __align__(16) ushort As[BM * BK];  // 8 KB, fragment-ordered 16B chunks
    __shared__ __align__(16) ushort Bs[BN * BK];  // 4 KB
    int tid = threadIdx.x;
    int lane = tid & 63;
    int wid = tid >> 6;
    int bm = blockIdx.x * BM;
    int bn = blockIdx.y * BN;
    int wm = (wid & 1) * 64;
    int wn = (wid >> 1) * 32;

    f32x4 acc[4][2] = {};

    for (int k0 = 0; k0 < K; k0 += BK) {
        __syncthreads();
        // stage A: 512 16B chunks (row, kq) -> frag order j = (row/16)*64 + kq*16 + row%16
#pragma unroll
        for (int u = 0; u < 2; u++) {
            int l = u * 256 + tid;
            int row = l >> 2, kq = l & 3;
            int gm = bm + row;
            uint4 v = make_uint4(0u, 0u, 0u, 0u);
            if (gm < M) v = *(const uint4*)(A + (size_t)gm * K + k0 + kq * 8);
            int j = ((row >> 4) << 6) + (kq << 4) + (row & 15);
            *(uint4*)(As + j * 8) = v;
        }
        // stage B: 256 chunks
        {
            int row = tid >> 2, kq = tid & 3;
            uint4 v = *(const uint4*)(Bt + (size_t)(bn + row) * K + k0 + kq * 8);
            int j = ((row >> 4) << 6) + (kq << 4) + (row & 15);
            *(uint4*)(Bs + j * 8) = v;
        }
        __syncthreads();
        short8 af[4], bfr[2];
#pragma unroll
        for (int i = 0; i < 4; i++) {
            int j = (((wm >> 4) + i) << 6) + ((lane >> 4) << 4) + (lane & 15);
            af[i] = *(const short8*)(As + j * 8);
        }
#pragma unroll
        for (int i = 0; i < 2; i++) {
            int j = (((wn >> 4) + i) << 6) + ((lane >> 4) << 4) + (lane & 15);
            bfr[i] = *(const short8*)(Bs + j * 8);
        }
#pragma unroll
        for (int i = 0; i < 4; i++)
#pragma unroll
            for (int jn = 0; jn < 2; jn++)
                acc[i][jn] = __builtin_amdgcn_mfma_f32_16x16x32_bf16(af[i], bfr[jn], acc[i][jn], 0, 0, 0);
    }

#pragma unroll
    for (int i = 0; i < 4; i++) {
#pragma unroll
        for (int jn = 0; jn < 2; jn++) {
            int col = bn + wn + jn * 16 + (lane & 15);
            float bv = bias[col];
#pragma unroll
            for (int r = 0; r < 4; r++) {
                int gm = bm + wm + i * 16 + ((lane >> 4) << 2) + r;
                if (gm < M) {
                    float v = acc[i][jn][r] + bv;
                    if (EPI == 1) {
                        v = fmaxf(v, 0.f) * scale[gm];
                        ((ushort*)Cout)[(size_t)gm * N + col] = f2b(v);
                    } else {
                        ((float*)Cout)[(size_t)gm * N + col] = v;
                    }
                }
            }
        }
    }
}

extern "C" void kernel_launch(void* const* d_in, const int* in_sizes, int n_in,
                              void* d_out, int out_size, void* d_ws, size_t ws_size,
                              hipStream_t stream) {
    const float* feat = (const float*)d_in[0];
    const int* ei = (const int*)d_in[1];
    const float* W1 = (const float*)d_in[2];
    const float* b1 = (const float*)d_in[3];
    const float* W2 = (const float*)d_in[4];
    const float* b2 = (const float*)d_in[5];
    float* out = (float*)d_out;

    const int* src = ei;
    const int* dst = ei + NE;

    char* ws = (char*)d_ws;
    size_t off = 0;
    auto alloc = [&](size_t bytes) -> void* {
        void* p = ws + off;
        off += (bytes + 255) & ~(size_t)255;
        return p;
    };
    int* deg = (int*)alloc(2 * 10240 * sizeof(int));
    int* deg_out = deg;
    int* deg_in = deg + 10240;
    int* row_off = (int*)alloc((NN + 16) * sizeof(int));
    int* cursor = (int*)alloc(NN * sizeof(int));
    float* norm_src = (float*)alloc(NN * sizeof(float));
    float* norm_dst = (float*)alloc(NN * sizeof(float));
    int* csr_src = (int*)alloc(NE * sizeof(int));
    ushort* featb = (ushort*)alloc((size_t)NN * IN_DIM * 2);      // 2.56 MB
    ushort* W1t = (ushort*)alloc((size_t)HID_DIM * IN_DIM * 2);   // [512][128]
    ushort* W2t = (ushort*)alloc((size_t)OUT_DIM * HID_DIM * 2);  // [512][512]
    ushort* agg1b = (ushort*)alloc((size_t)NN * IN_DIM * 2);
    ushort* hb = (ushort*)alloc((size_t)NN * HID_DIM * 2);        // 10.24 MB
    ushort* agg2b = (ushort*)alloc((size_t)NN * HID_DIM * 2);     // 10.24 MB

    zero_int_kernel<<<(2 * 10240 + 255) / 256, 256, 0, stream>>>(deg, 2 * 10240);
    degree_kernel<<<(NE + 255) / 256, 256, 0, stream>>>(src, dst, deg_out, deg_in, NE);
    scan_kernel<<<1, 1024, 0, stream>>>(deg_in, row_off, cursor, NN);
    norm_kernel<<<(NN + 255) / 256, 256, 0, stream>>>(deg_out, deg_in, norm_src, norm_dst, NN);
    csr_fill_kernel<<<(NE + 255) / 256, 256, 0, stream>>>(src, dst, cursor, csr_src, NE);

    featconv_kernel<<<(NN * IN_DIM / 4 + 255) / 256, 256, 0, stream>>>(feat, norm_src, featb);
    {
        dim3 g1(IN_DIM / 32, HID_DIM / 32);
        transpose_bf16_kernel<<<g1, 256, 0, stream>>>(W1, W1t, IN_DIM, HID_DIM);
        dim3 g2(HID_DIM / 32, OUT_DIM / 32);
        transpose_bf16_kernel<<<g2, 256, 0, stream>>>(W2, W2t, HID_DIM, OUT_DIM);
    }

    // Layer 1
    agg1_kernel<<<NN, 64, 0, stream>>>((const uint*)featb, row_off, csr_src, norm_dst, (uint*)agg1b);
    {
        dim3 grid((NN + 127) / 128, HID_DIM / 64);
        gemm_bf16_kernel<1><<<grid, 256, 0, stream>>>(agg1b, W1t, b1, norm_src, hb, NN, IN_DIM, HID_DIM);
    }
    // Layer 2
    agg2_kernel<<<NN, 256, 0, stream>>>((const uint*)hb, row_off, csr_src, norm_dst, (uint*)agg2b);
    {
        dim3 grid((NN + 127) / 128, OUT_DIM / 64);
        gemm_bf16_kernel<0><<<grid, 256, 0, stream>>>(agg2b, W2t, b2, nullptr, out, NN, HID_DIM, OUT_DIM);
    }
}

// Round 3
// 144.816 us; speedup vs baseline: 3.0238x; 1.7239x over previous
//
#include <hip/hip_runtime.h>

#define NN 10000
#define NE 640000
#define IN_DIM 128
#define HID_DIM 512
#define OUT_DIM 512
#define NB 10240          // padded bin count (>= NN, mult of 1024)
#define P_PART 128
#define EPB (NE / P_PART) // 5000 edges per partition

typedef __attribute__((ext_vector_type(8))) short short8;
typedef __attribute__((ext_vector_type(4))) float f32x4;

__device__ __forceinline__ ushort f2b(float f) {
    union { float f; uint i; } c; c.f = f;
    uint x = c.i;
    uint r = (x + 0x7fffu + ((x >> 16) & 1u)) >> 16;
    return (ushort)r;
}
__device__ __forceinline__ float blo(uint a) {
    union { uint i; float f; } c; c.i = a << 16; return c.f;
}
__device__ __forceinline__ float bhi(uint a) {
    union { uint i; float f; } c; c.i = a & 0xffff0000u; return c.f;
}

// Per-partition LDS histogram. blockIdx.x = partition, blockIdx.y selects dst(0)/src(1).
__global__ __launch_bounds__(1024) void hist_kernel(const int* __restrict__ ei,
                                                    int* __restrict__ pcnt_dst,
                                                    int* __restrict__ pcnt_src) {
    __shared__ int h[NB];
    int p = blockIdx.x;
    const int* __restrict__ idx = (blockIdx.y == 0) ? (ei + NE) : ei;
    int* __restrict__ outp = (blockIdx.y == 0) ? pcnt_dst : pcnt_src;
    int t = threadIdx.x;
    for (int i = t; i < NB; i += 1024) h[i] = 0;
    __syncthreads();
    int base = p * EPB;
    for (int i = t; i < EPB; i += 1024) atomicAdd(&h[idx[base + i]], 1);
    __syncthreads();
    for (int i = t; i < NB; i += 1024) outp[p * NB + i] = h[i];
}

// Column reduce over partitions: deg_in, exclusive poff[p][v], norms.
__global__ __launch_bounds__(256) void colreduce_kernel(const int* __restrict__ pcnt_dst,
                                                        const int* __restrict__ pcnt_src,
                                                        int* __restrict__ poff,
                                                        int* __restrict__ deg_in,
                                                        float* __restrict__ norm_src,
                                                        float* __restrict__ norm_dst) {
    int v = blockIdx.x * 256 + threadIdx.x;  // 0..NB-1
    int s = 0;
#pragma unroll 4
    for (int p = 0; p < P_PART; p++) {
        int c = pcnt_dst[p * NB + v];
        poff[p * NB + v] = s;
        s += c;
    }
    deg_in[v] = s;
    int s2 = 0;
#pragma unroll 4
    for (int p = 0; p < P_PART; p++) s2 += pcnt_src[p * NB + v];
    if (v < NN) {
        norm_dst[v] = rsqrtf(fmaxf((float)s, 1.0f));
        norm_src[v] = rsqrtf(fmaxf((float)s2, 1.0f));
    }
}

// Single-block exclusive scan of deg[0..NB) -> row_off.
__global__ __launch_bounds__(1024) void scan_kernel(const int* __restrict__ deg,
                                                    int* __restrict__ row_off) {
    const int PER = NB / 1024;  // 10
    __shared__ int lds[1024];
    int t = threadIdx.x;
    int base = t * PER;
    int local[PER];
    int s = 0;
#pragma unroll
    for (int i = 0; i < PER; i++) {
        int v = deg[base + i];
        local[i] = s;
        s += v;
    }
    lds[t] = s;
    __syncthreads();
    for (int off = 1; off < 1024; off <<= 1) {
        int x = (t >= off) ? lds[t - off] : 0;
        __syncthreads();
        lds[t] += x;
        __syncthreads();
    }
    int excl = lds[t] - s;
#pragma unroll
    for (int i = 0; i < PER; i++) {
        int idx = base + i;
        if (idx <= NN) row_off[idx] = excl + local[i];
    }
}

// CSR fill with LDS-local cursors (no global atomics).
__global__ __launch_bounds__(1024) void fill_kernel(const int* __restrict__ src,
                                                    const int* __restrict__ dst,
                                                    const int* __restrict__ row_off,
                                                    const int* __restrict__ poff,
                                                    int* __restrict__ csr_src) {
    __shared__ int cur[NB];
    int p = blockIdx.x, t = threadIdx.x;
    for (int i = t; i < NB; i += 1024)
        cur[i] = ((i < NN) ? row_off[i] : 0) + poff[p * NB + i];
    __syncthreads();
    int base = p * EPB;
    for (int i = t; i < EPB; i += 1024) {
        int d = dst[base + i];
        int slot = atomicAdd(&cur[d], 1);
        csr_src[slot] = src[base + i];
    }
}

// featb[u][d] = bf16(feat[u][d] * norm_src[u])
__global__ void featconv_kernel(const float* __restrict__ feat,
                                const float* __restrict__ norm_src,
                                ushort* __restrict__ featb) {
    int i = blockIdx.x * blockDim.x + threadIdx.x;  // float4 index
    if (i < NN * IN_DIM / 4) {
        float4 v = ((const float4*)feat)[i];
        float s = norm_src[i >> 5];
        ushort4 o;
        o.x = f2b(v.x * s); o.y = f2b(v.y * s); o.z = f2b(v.z * s); o.w = f2b(v.w * s);
        ((ushort4*)featb)[i] = o;
    }
}

// Wt[n][k] = bf16(W[k][n])
__global__ __launch_bounds__(256) void transpose_bf16_kernel(const float* __restrict__ W,
                                                             ushort* __restrict__ Wt,
                                                             int K, int N) {
    __shared__ float t[32][33];
    int k0 = blockIdx.x * 32, n0 = blockIdx.y * 32;
    int tx = threadIdx.x & 31, ty = threadIdx.x >> 5;
#pragma unroll
    for (int r = 0; r < 32; r += 8)
        t[ty + r][tx] = W[(size_t)(k0 + ty + r) * N + n0 + tx];
    __syncthreads();
#pragma unroll
    for (int r = 0; r < 32; r += 8)
        Wt[(size_t)(n0 + ty + r) * K + k0 + tx] = f2b(t[tx][ty + r]);
}

// One wave per node; 128 bf16 dims = 64 uints. Unroll 8.
__global__ __launch_bounds__(64) void agg1_kernel(const uint* __restrict__ fb,
                                                  const int* __restrict__ row_off,
                                                  const int* __restrict__ csr_src,
                                                  const float* __restrict__ norm_dst,
                                                  uint* __restrict__ aggb) {
    int node = blockIdx.x;
    int lane = threadIdx.x;
    int beg = row_off[node], end = row_off[node + 1];
    float s0 = 0.f, s1 = 0.f;
    int i = beg;
    for (; i + 7 < end; i += 8) {
        int u[8]; uint a[8];
#pragma unroll
        for (int j = 0; j < 8; j++) u[j] = csr_src[i + j];
#pragma unroll
        for (int j = 0; j < 8; j++) a[j] = fb[u[j] * 64 + lane];
#pragma unroll
        for (int j = 0; j < 8; j++) { s0 += blo(a[j]); s1 += bhi(a[j]); }
    }
    for (; i < end; i++) {
        uint a = fb[csr_src[i] * 64 + lane];
        s0 += blo(a); s1 += bhi(a);
    }
    float nd = norm_dst[node];
    aggb[node * 64 + lane] = (uint)f2b(s0 * nd) | ((uint)f2b(s1 * nd) << 16);
}

// Sliced 512-dim gather: grid (NN, 4); one wave handles 128 dims (64 uints) of one node.
// Each slice's working set = 2.56 MB -> fits per-XCD L2.
__global__ __launch_bounds__(64) void agg2_kernel(const uint* __restrict__ hb,
                                                  const int* __restrict__ row_off,
                                                  const int* __restrict__ csr_src,
                                                  const float* __restrict__ norm_dst,
                                                  uint* __restrict__ aggb) {
    int node = blockIdx.x;
    int t = blockIdx.y * 64 + threadIdx.x;  // uint index 0..255
    int beg = row_off[node], end = row_off[node + 1];
    float s0 = 0.f, s1 = 0.f;
    int i = beg;
    for (; i + 7 < end; i += 8) {
        int u[8]; uint a[8];
#pragma unroll
        for (int j = 0; j < 8; j++) u[j] = csr_src[i + j];
#pragma unroll
        for (int j = 0; j < 8; j++) a[j] = hb[u[j] * 256 + t];
#pragma unroll
        for (int j = 0; j < 8; j++) { s0 += blo(a[j]); s1 += bhi(a[j]); }
    }
    for (; i < end; i++) {
        uint a = hb[csr_src[i] * 256 + t];
        s0 += blo(a); s1 += bhi(a);
    }
    float nd = norm_dst[node];
    aggb[node * 256 + t] = (uint)f2b(s0 * nd) | ((uint)f2b(s1 * nd) << 16);
}

// bf16 MFMA GEMM: C[M][N] = A[M][K] @ Bt[N][K]^T (+bias).
// BM=128 BN=64 BK=32, 256 threads = 4 waves (2x2), fragment-ordered LDS.
// EPI 0: fp32 out = acc + bias.   EPI 1: bf16 out = relu(acc+bias) * scale[row].
template <int EPI>
__global__ __launch_bounds__(256) void gemm_bf16_kernel(const ushort* __restrict__ A,
                                                        const ushort* __restrict__ Bt,
                                                        const float* __restrict__ bias,
                                                        const float* __restrict__ scale,
                                                        void* __restrict__ Cout,
                                                        int M, int K, int N) {
    const int BM = 128;
    __shared__ __align__(16) ushort As[BM * 32];
    __shared__ __align__(16) ushort Bs[64 * 32];
    int tid = threadIdx.x;
    int lane = tid & 63;
    int wid = tid >> 6;
    int bm = blockIdx.x * BM;
    int bn = blockIdx.y * 64;
    int wm = (wid & 1) * 64;
    int wn = (wid >> 1) * 32;

    f32x4 acc[4][2] = {};

    for (int k0 = 0; k0 < K; k0 += 32) {
        __syncthreads();
#pragma unroll
        for (int u = 0; u < 2; u++) {
            int l = u * 256 + tid;
            int row = l >> 2, kq = l & 3;
            int gm = bm + row;
            uint4 v = make_uint4(0u, 0u, 0u, 0u);
            if (gm < M) v = *(const uint4*)(A + (size_t)gm * K + k0 + kq * 8);
            int j = ((row >> 4) << 6) + (kq << 4) + (row & 15);
            *(uint4*)(As + j * 8) = v;
        }
        {
            int row = tid >> 2, kq = tid & 3;
            uint4 v = *(const uint4*)(Bt + (size_t)(bn + row) * K + k0 + kq * 8);
            int j = ((row >> 4) << 6) + (kq << 4) + (row & 15);
            *(uint4*)(Bs + j * 8) = v;
        }
        __syncthreads();
        short8 af[4], bfr[2];
#pragma unroll
        for (int i = 0; i < 4; i++) {
            int j = (((wm >> 4) + i) << 6) + ((lane >> 4) << 4) + (lane & 15);
            af[i] = *(const short8*)(As + j * 8);
        }
#pragma unroll
        for (int i = 0; i < 2; i++) {
            int j = (((wn >> 4) + i) << 6) + ((lane >> 4) << 4) + (lane & 15);
            bfr[i] = *(const short8*)(Bs + j * 8);
        }
#pragma unroll
        for (int i = 0; i < 4; i++)
#pragma unroll
            for (int jn = 0; jn < 2; jn++)
                acc[i][jn] = __builtin_amdgcn_mfma_f32_16x16x32_bf16(af[i], bfr[jn], acc[i][jn], 0, 0, 0);
    }

#pragma unroll
    for (int i = 0; i < 4; i++) {
#pragma unroll
        for (int jn = 0; jn < 2; jn++) {
            int col = bn + wn + jn * 16 + (lane & 15);
            float bv = bias[col];
#pragma unroll
            for (int r = 0; r < 4; r++) {
                int gm = bm + wm + i * 16 + ((lane >> 4) << 2) + r;
                if (gm < M) {
                    float v = acc[i][jn][r] + bv;
                    if (EPI == 1) {
                        v = fmaxf(v, 0.f) * scale[gm];
                        ((ushort*)Cout)[(size_t)gm * N + col] = f2b(v);
                    } else {
                        ((float*)Cout)[(size_t)gm * N + col] = v;
                    }
                }
            }
        }
    }
}

extern "C" void kernel_launch(void* const* d_in, const int* in_sizes, int n_in,
                              void* d_out, int out_size, void* d_ws, size_t ws_size,
                              hipStream_t stream) {
    const float* feat = (const float*)d_in[0];
    const int* ei = (const int*)d_in[1];
    const float* W1 = (const float*)d_in[2];
    const float* b1 = (const float*)d_in[3];
    const float* W2 = (const float*)d_in[4];
    const float* b2 = (const float*)d_in[5];
    float* out = (float*)d_out;

    const int* src = ei;
    const int* dst = ei + NE;

    char* ws = (char*)d_ws;
    size_t off = 0;
    auto alloc = [&](size_t bytes) -> void* {
        void* p = ws + off;
        off += (bytes + 255) & ~(size_t)255;
        return p;
    };
    // ---- fixed region ----
    int* row_off = (int*)alloc((NN + 16) * sizeof(int));
    int* deg_in = (int*)alloc(NB * sizeof(int));
    float* norm_src = (float*)alloc(NN * sizeof(float));
    float* norm_dst = (float*)alloc(NN * sizeof(float));
    int* csr_src = (int*)alloc(NE * sizeof(int));
    ushort* featb = (ushort*)alloc((size_t)NN * IN_DIM * 2);
    ushort* W1t = (ushort*)alloc((size_t)HID_DIM * IN_DIM * 2);
    ushort* W2t = (ushort*)alloc((size_t)OUT_DIM * HID_DIM * 2);
    // ---- union region: prep {pcnt_dst, pcnt_src, poff} overlaps main {agg1b, hb, agg2b} ----
    size_t union_base = off;
    int* pcnt_dst = (int*)alloc((size_t)P_PART * NB * sizeof(int));  // 5.24 MB
    int* pcnt_src = (int*)alloc((size_t)P_PART * NB * sizeof(int));  // 5.24 MB
    int* poff = (int*)alloc((size_t)P_PART * NB * sizeof(int));      // 5.24 MB
    off = union_base;
    ushort* agg1b = (ushort*)alloc((size_t)NN * IN_DIM * 2);   // 2.56 MB
    ushort* hb = (ushort*)alloc((size_t)NN * HID_DIM * 2);     // 10.24 MB
    ushort* agg2b = (ushort*)alloc((size_t)NN * HID_DIM * 2);  // 10.24 MB

    // ---- graph prep (no global atomics) ----
    {
        dim3 g(P_PART, 2);
        hist_kernel<<<g, 1024, 0, stream>>>(ei, pcnt_dst, pcnt_src);
    }
    colreduce_kernel<<<NB / 256, 256, 0, stream>>>(pcnt_dst, pcnt_src, poff, deg_in, norm_src, norm_dst);
    scan_kernel<<<1, 1024, 0, stream>>>(deg_in, row_off);
    fill_kernel<<<P_PART, 1024, 0, stream>>>(src, dst, row_off, poff, csr_src);

    // ---- dense prep ----
    featconv_kernel<<<(NN * IN_DIM / 4 + 255) / 256, 256, 0, stream>>>(feat, norm_src, featb);
    {
        dim3 g1(IN_DIM / 32, HID_DIM / 32);
        transpose_bf16_kernel<<<g1, 256, 0, stream>>>(W1, W1t, IN_DIM, HID_DIM);
        dim3 g2(HID_DIM / 32, OUT_DIM / 32);
        transpose_bf16_kernel<<<g2, 256, 0, stream>>>(W2, W2t, HID_DIM, OUT_DIM);
    }

    // ---- layer 1 ----
    agg1_kernel<<<NN, 64, 0, stream>>>((const uint*)featb, row_off, csr_src, norm_dst, (uint*)agg1b);
    {
        dim3 grid((NN + 127) / 128, HID_DIM / 64);
        gemm_bf16_kernel<1><<<grid, 256, 0, stream>>>(agg1b, W1t, b1, norm_src, hb, NN, IN_DIM, HID_DIM);
    }
    // ---- layer 2 ----
    {
        dim3 grid(NN, 4);
        agg2_kernel<<<grid, 64, 0, stream>>>((const uint*)hb, row_off, csr_src, norm_dst, (uint*)agg2b);
    }
    {
        dim3 grid((NN + 127) / 128, OUT_DIM / 64);
        gemm_bf16_kernel<0><<<grid, 256, 0, stream>>>(agg2b, W2t, b2, nullptr, out, NN, HID_DIM, OUT_DIM);
    }
}

// Round 4
// 137.808 us; speedup vs baseline: 3.1776x; 1.0509x over previous
//
#include <hip/hip_runtime.h>

#define NN 10000
#define NE 640000
#define IN_DIM 128
#define HID_DIM 512
#define OUT_DIM 512
#define NB 10240          // padded bin count (>= NN, mult of 1024)
#define P_PART 128
#define EPB (NE / P_PART) // 5000 edges per partition

typedef __attribute__((ext_vector_type(8))) short short8;
typedef __attribute__((ext_vector_type(4))) float f32x4;
typedef __attribute__((ext_vector_type(2))) float f32x2;

__device__ __forceinline__ ushort f2b(float f) {
    union { float f; uint i; } c; c.f = f;
    uint x = c.i;
    uint r = (x + 0x7fffu + ((x >> 16) & 1u)) >> 16;
    return (ushort)r;
}
__device__ __forceinline__ float blo(uint a) {
    union { uint i; float f; } c; c.i = a << 16; return c.f;
}
__device__ __forceinline__ float bhi(uint a) {
    union { uint i; float f; } c; c.i = a & 0xffff0000u; return c.f;
}

// Per-partition LDS histogram. blockIdx.x = partition, blockIdx.y selects dst(0)/src(1).
__global__ __launch_bounds__(1024) void hist_kernel(const int* __restrict__ ei,
                                                    ushort* __restrict__ pcnt_dst,
                                                    ushort* __restrict__ pcnt_src) {
    __shared__ int h[NB];
    int p = blockIdx.x;
    const int* __restrict__ idx = (blockIdx.y == 0) ? (ei + NE) : ei;
    ushort* __restrict__ outp = (blockIdx.y == 0) ? pcnt_dst : pcnt_src;
    int t = threadIdx.x;
    for (int i = t; i < NB; i += 1024) h[i] = 0;
    __syncthreads();
    int base = p * EPB;
    for (int i = t; i < EPB; i += 1024) atomicAdd(&h[idx[base + i]], 1);
    __syncthreads();
    for (int i = t; i < NB; i += 1024) outp[p * NB + i] = (ushort)h[i];
}

// Column reduce over partitions: deg_in, exclusive poff[p][v], norms.
__global__ __launch_bounds__(256) void colreduce_kernel(const ushort* __restrict__ pcnt_dst,
                                                        const ushort* __restrict__ pcnt_src,
                                                        int* __restrict__ poff,
                                                        int* __restrict__ deg_in,
                                                        float* __restrict__ norm_src,
                                                        float* __restrict__ norm_dst) {
    int v = blockIdx.x * 256 + threadIdx.x;  // 0..NB-1
    int s = 0;
#pragma unroll 4
    for (int p = 0; p < P_PART; p++) {
        int c = pcnt_dst[p * NB + v];
        poff[p * NB + v] = s;
        s += c;
    }
    deg_in[v] = s;
    int s2 = 0;
#pragma unroll 4
    for (int p = 0; p < P_PART; p++) s2 += pcnt_src[p * NB + v];
    if (v < NN) {
        norm_dst[v] = rsqrtf(fmaxf((float)s, 1.0f));
        norm_src[v] = rsqrtf(fmaxf((float)s2, 1.0f));
    }
}

// Single-block exclusive scan of deg[0..NB) -> row_off.
__global__ __launch_bounds__(1024) void scan_kernel(const int* __restrict__ deg,
                                                    int* __restrict__ row_off) {
    const int PER = NB / 1024;  // 10
    __shared__ int lds[1024];
    int t = threadIdx.x;
    int base = t * PER;
    int local[PER];
    int s = 0;
#pragma unroll
    for (int i = 0; i < PER; i++) {
        int v = deg[base + i];
        local[i] = s;
        s += v;
    }
    lds[t] = s;
    __syncthreads();
    for (int off = 1; off < 1024; off <<= 1) {
        int x = (t >= off) ? lds[t - off] : 0;
        __syncthreads();
        lds[t] += x;
        __syncthreads();
    }
    int excl = lds[t] - s;
#pragma unroll
    for (int i = 0; i < PER; i++) {
        int idx = base + i;
        if (idx <= NN) row_off[idx] = excl + local[i];
    }
}

// CSR fill with LDS-local cursors (no global atomics).
__global__ __launch_bounds__(1024) void fill_kernel(const int* __restrict__ src,
                                                    const int* __restrict__ dst,
                                                    const int* __restrict__ row_off,
                                                    const int* __restrict__ poff,
                                                    int* __restrict__ csr_src) {
    __shared__ int cur[NB];
    int p = blockIdx.x, t = threadIdx.x;
    for (int i = t; i < NB; i += 1024)
        cur[i] = ((i < NN) ? row_off[i] : 0) + poff[p * NB + i];
    __syncthreads();
    int base = p * EPB;
    for (int i = t; i < EPB; i += 1024) {
        int d = dst[base + i];
        int slot = atomicAdd(&cur[d], 1);
        csr_src[slot] = src[base + i];
    }
}

// Fused dense prep: blocks [0,1250) featconv; [1250,1314) W1 transpose; [1314,1570) W2 transpose.
__global__ __launch_bounds__(256) void densep_kernel(const float* __restrict__ feat,
                                                     const float* __restrict__ norm_src,
                                                     ushort* __restrict__ featb,
                                                     const float* __restrict__ W1,
                                                     ushort* __restrict__ W1t,
                                                     const float* __restrict__ W2,
                                                     ushort* __restrict__ W2t) {
    __shared__ float tld[32][33];
    int b = blockIdx.x;
    if (b < 1250) {
        int i = b * 256 + threadIdx.x;  // float4 index
        if (i < NN * IN_DIM / 4) {
            float4 v = ((const float4*)feat)[i];
            float s = norm_src[i >> 5];
            ushort4 o;
            o.x = f2b(v.x * s); o.y = f2b(v.y * s); o.z = f2b(v.z * s); o.w = f2b(v.w * s);
            ((ushort4*)featb)[i] = o;
        }
        return;
    }
    const float* W; ushort* Wt; int K, N, k0, n0;
    if (b < 1250 + 64) {
        int bb = b - 1250;
        W = W1; Wt = W1t; K = IN_DIM; N = HID_DIM;
        k0 = (bb & 3) * 32; n0 = (bb >> 2) * 32;
    } else {
        int bb = b - 1250 - 64;
        W = W2; Wt = W2t; K = HID_DIM; N = OUT_DIM;
        k0 = (bb & 15) * 32; n0 = (bb >> 4) * 32;
    }
    int tx = threadIdx.x & 31, ty = threadIdx.x >> 5;
#pragma unroll
    for (int r = 0; r < 32; r += 8)
        tld[ty + r][tx] = W[(size_t)(k0 + ty + r) * N + n0 + tx];
    __syncthreads();
#pragma unroll
    for (int r = 0; r < 32; r += 8)
        Wt[(size_t)(n0 + ty + r) * K + k0 + tx] = f2b(tld[tx][ty + r]);
}

// One wave per node; 128 bf16 dims = 64 uints. Unroll 8, 32-bit saddr-form gathers.
__global__ __launch_bounds__(64) void agg1_kernel(const uint* __restrict__ fb,
                                                  const int* __restrict__ row_off,
                                                  const int* __restrict__ csr_src,
                                                  const float* __restrict__ norm_dst,
                                                  uint* __restrict__ aggb) {
    int node = blockIdx.x;
    uint lane = threadIdx.x;
    int beg = row_off[node], end = row_off[node + 1];
    f32x2 acc = {0.f, 0.f};
    int i = beg;
    for (; i + 7 < end; i += 8) {
        uint u[8]; uint a[8];
#pragma unroll
        for (int j = 0; j < 8; j++) u[j] = (uint)csr_src[i + j];
#pragma unroll
        for (int j = 0; j < 8; j++) a[j] = fb[u[j] * 64u + lane];
#pragma unroll
        for (int j = 0; j < 8; j++) {
            f32x2 v; v.x = blo(a[j]); v.y = bhi(a[j]);
            acc += v;
        }
    }
    for (; i < end; i++) {
        uint a = fb[(uint)csr_src[i] * 64u + lane];
        f32x2 v; v.x = blo(a); v.y = bhi(a);
        acc += v;
    }
    float nd = norm_dst[node];
    aggb[node * 64 + lane] = (uint)f2b(acc.x * nd) | ((uint)f2b(acc.y * nd) << 16);
}

// Sliced 512-dim gather: grid (NN, 4); one wave handles 128 dims (64 uints) of one node.
// Slice working set = 2.56 MB -> per-XCD L2 resident. 32-bit saddr-form gathers.
__global__ __launch_bounds__(64) void agg2_kernel(const uint* __restrict__ hb,
                                                  const int* __restrict__ row_off,
                                                  const int* __restrict__ csr_src,
                                                  const float* __restrict__ norm_dst,
                                                  uint* __restrict__ aggb) {
    int node = blockIdx.x;
    uint t = blockIdx.y * 64 + threadIdx.x;  // uint index 0..255
    int beg = row_off[node], end = row_off[node + 1];
    f32x2 acc = {0.f, 0.f};
    int i = beg;
    for (; i + 7 < end; i += 8) {
        uint u[8]; uint a[8];
#pragma unroll
        for (int j = 0; j < 8; j++) u[j] = (uint)csr_src[i + j];
#pragma unroll
        for (int j = 0; j < 8; j++) a[j] = hb[u[j] * 256u + t];
#pragma unroll
        for (int j = 0; j < 8; j++) {
            f32x2 v; v.x = blo(a[j]); v.y = bhi(a[j]);
            acc += v;
        }
    }
    for (; i < end; i++) {
        uint a = hb[(uint)csr_src[i] * 256u + t];
        f32x2 v; v.x = blo(a); v.y = bhi(a);
        acc += v;
    }
    float nd = norm_dst[node];
    aggb[node * 256 + t] = (uint)f2b(acc.x * nd) | ((uint)f2b(acc.y * nd) << 16);
}

// bf16 MFMA GEMM: C[M][N] = A[M][K] @ Bt[N][K]^T (+bias).
// BM=128 BN=64 BK=32, 256 threads = 4 waves (2x2), fragment-ordered LDS.
// EPI 0: fp32 out = acc + bias.   EPI 1: bf16 out = relu(acc+bias) * scale[row].
template <int EPI>
__global__ __launch_bounds__(256) void gemm_bf16_kernel(const ushort* __restrict__ A,
                                                        const ushort* __restrict__ Bt,
                                                        const float* __restrict__ bias,
                                                        const float* __restrict__ scale,
                                                        void* __restrict__ Cout,
                                                        int M, int K, int N) {
    const int BM = 128;
    __shared__ __align__(16) ushort As[BM * 32];
    __shared__ __align__(16) ushort Bs[64 * 32];
    int tid = threadIdx.x;
    int lane = tid & 63;
    int wid = tid >> 6;
    int bm = blockIdx.x * BM;
    int bn = blockIdx.y * 64;
    int wm = (wid & 1) * 64;
    int wn = (wid >> 1) * 32;

    f32x4 acc[4][2] = {};

    for (int k0 = 0; k0 < K; k0 += 32) {
        __syncthreads();
#pragma unroll
        for (int u = 0; u < 2; u++) {
            int l = u * 256 + tid;
            int row = l >> 2, kq = l & 3;
            int gm = bm + row;
            uint4 v = make_uint4(0u, 0u, 0u, 0u);
            if (gm < M) v = *(const uint4*)(A + (size_t)gm * K + k0 + kq * 8);
            int j = ((row >> 4) << 6) + (kq << 4) + (row & 15);
            *(uint4*)(As + j * 8) = v;
        }
        {
            int row = tid >> 2, kq = tid & 3;
            uint4 v = *(const uint4*)(Bt + (size_t)(bn + row) * K + k0 + kq * 8);
            int j = ((row >> 4) << 6) + (kq << 4) + (row & 15);
            *(uint4*)(Bs + j * 8) = v;
        }
        __syncthreads();
        short8 af[4], bfr[2];
#pragma unroll
        for (int i = 0; i < 4; i++) {
            int j = (((wm >> 4) + i) << 6) + ((lane >> 4) << 4) + (lane & 15);
            af[i] = *(const short8*)(As + j * 8);
        }
#pragma unroll
        for (int i = 0; i < 2; i++) {
            int j = (((wn >> 4) + i) << 6) + ((lane >> 4) << 4) + (lane & 15);
            bfr[i] = *(const short8*)(Bs + j * 8);
        }
#pragma unroll
        for (int i = 0; i < 4; i++)
#pragma unroll
            for (int jn = 0; jn < 2; jn++)
                acc[i][jn] = __builtin_amdgcn_mfma_f32_16x16x32_bf16(af[i], bfr[jn], acc[i][jn], 0, 0, 0);
    }

#pragma unroll
    for (int i = 0; i < 4; i++) {
#pragma unroll
        for (int jn = 0; jn < 2; jn++) {
            int col = bn + wn + jn * 16 + (lane & 15);
            float bv = bias[col];
#pragma unroll
            for (int r = 0; r < 4; r++) {
                int gm = bm + wm + i * 16 + ((lane >> 4) << 2) + r;
                if (gm < M) {
                    float v = acc[i][jn][r] + bv;
                    if (EPI == 1) {
                        v = fmaxf(v, 0.f) * scale[gm];
                        ((ushort*)Cout)[(size_t)gm * N + col] = f2b(v);
                    } else {
                        ((float*)Cout)[(size_t)gm * N + col] = v;
                    }
                }
            }
        }
    }
}

extern "C" void kernel_launch(void* const* d_in, const int* in_sizes, int n_in,
                              void* d_out, int out_size, void* d_ws, size_t ws_size,
                              hipStream_t stream) {
    const float* feat = (const float*)d_in[0];
    const int* ei = (const int*)d_in[1];
    const float* W1 = (const float*)d_in[2];
    const float* b1 = (const float*)d_in[3];
    const float* W2 = (const float*)d_in[4];
    const float* b2 = (const float*)d_in[5];
    float* out = (float*)d_out;

    const int* src = ei;
    const int* dst = ei + NE;

    char* ws = (char*)d_ws;
    size_t off = 0;
    auto alloc = [&](size_t bytes) -> void* {
        void* p = ws + off;
        off += (bytes + 255) & ~(size_t)255;
        return p;
    };
    // ---- fixed region ----
    int* row_off = (int*)alloc((NN + 16) * sizeof(int));
    int* deg_in = (int*)alloc(NB * sizeof(int));
    float* norm_src = (float*)alloc(NN * sizeof(float));
    float* norm_dst = (float*)alloc(NN * sizeof(float));
    int* csr_src = (int*)alloc(NE * sizeof(int));
    ushort* featb = (ushort*)alloc((size_t)NN * IN_DIM * 2);
    ushort* W1t = (ushort*)alloc((size_t)HID_DIM * IN_DIM * 2);
    ushort* W2t = (ushort*)alloc((size_t)OUT_DIM * HID_DIM * 2);
    // ---- union region: prep {pcnt_dst, pcnt_src, poff} overlaps main {agg1b, hb, agg2b} ----
    size_t union_base = off;
    ushort* pcnt_dst = (ushort*)alloc((size_t)P_PART * NB * sizeof(ushort));  // 2.62 MB
    ushort* pcnt_src = (ushort*)alloc((size_t)P_PART * NB * sizeof(ushort));  // 2.62 MB
    int* poff = (int*)alloc((size_t)P_PART * NB * sizeof(int));               // 5.24 MB
    off = union_base;
    ushort* agg1b = (ushort*)alloc((size_t)NN * IN_DIM * 2);   // 2.56 MB
    ushort* hb = (ushort*)alloc((size_t)NN * HID_DIM * 2);     // 10.24 MB
    ushort* agg2b = (ushort*)alloc((size_t)NN * HID_DIM * 2);  // 10.24 MB

    // ---- graph prep (no global atomics) ----
    {
        dim3 g(P_PART, 2);
        hist_kernel<<<g, 1024, 0, stream>>>(ei, pcnt_dst, pcnt_src);
    }
    colreduce_kernel<<<NB / 256, 256, 0, stream>>>(pcnt_dst, pcnt_src, poff, deg_in, norm_src, norm_dst);
    scan_kernel<<<1, 1024, 0, stream>>>(deg_in, row_off);
    fill_kernel<<<P_PART, 1024, 0, stream>>>(src, dst, row_off, poff, csr_src);

    // ---- dense prep (fused featconv + W transposes) ----
    densep_kernel<<<1250 + 64 + 256, 256, 0, stream>>>(feat, norm_src, featb, W1, W1t, W2, W2t);

    // ---- layer 1 ----
    agg1_kernel<<<NN, 64, 0, stream>>>((const uint*)featb, row_off, csr_src, norm_dst, (uint*)agg1b);
    {
        dim3 grid((NN + 127) / 128, HID_DIM / 64);
        gemm_bf16_kernel<1><<<grid, 256, 0, stream>>>(agg1b, W1t, b1, norm_src, hb, NN, IN_DIM, HID_DIM);
    }
    // ---- layer 2 ----
    {
        dim3 grid(NN, 4);
        agg2_kernel<<<grid, 64, 0, stream>>>((const uint*)hb, row_off, csr_src, norm_dst, (uint*)agg2b);
    }
    {
        dim3 grid((NN + 127) / 128, OUT_DIM / 64);
        gemm_bf16_kernel<0><<<grid, 256, 0, stream>>>(agg2b, W2t, b2, nullptr, out, NN, HID_DIM, OUT_DIM);
    }
}

// Round 5
// 136.294 us; speedup vs baseline: 3.2129x; 1.0111x over previous
//
#include <hip/hip_runtime.h>

#define NN 10000
#define NE 640000
#define IN_DIM 128
#define HID_DIM 512
#define OUT_DIM 512
#define NB 10240          // padded bin count (>= NN, mult of 1024)
#define P_PART 128
#define EPB (NE / P_PART) // 5000 edges per partition

typedef __attribute__((ext_vector_type(8))) short short8;
typedef __attribute__((ext_vector_type(4))) float f32x4;
typedef __attribute__((ext_vector_type(2))) float f32x2;

__device__ __forceinline__ ushort f2b(float f) {
    union { float f; uint i; } c; c.f = f;
    uint x = c.i;
    uint r = (x + 0x7fffu + ((x >> 16) & 1u)) >> 16;
    return (ushort)r;
}
__device__ __forceinline__ float blo(uint a) {
    union { uint i; float f; } c; c.i = a << 16; return c.f;
}
__device__ __forceinline__ float bhi(uint a) {
    union { uint i; float f; } c; c.i = a & 0xffff0000u; return c.f;
}

// Async global->LDS, 16B per lane, linear LDS dest (wave-uniform base + lane*16).
__device__ __forceinline__ void gl_lds16(const ushort* g, ushort* l) {
    __builtin_amdgcn_global_load_lds((const __attribute__((address_space(1))) uint*)g,
                                     (__attribute__((address_space(3))) uint*)l, 16, 0, 0);
}

// Fused: blocks [0,128) dst-hist, [128,256) src-hist, [256,320) W1^T, [320,576) W2^T.
__global__ __launch_bounds__(1024) void histw_kernel(const int* __restrict__ ei,
                                                     ushort* __restrict__ pcnt_dst,
                                                     ushort* __restrict__ pcnt_src,
                                                     const float* __restrict__ W1,
                                                     ushort* __restrict__ W1t,
                                                     const float* __restrict__ W2,
                                                     ushort* __restrict__ W2t) {
    __shared__ int h[NB];
    int b = blockIdx.x;
    int t = threadIdx.x;
    if (b < 256) {
        int p = b & 127;
        const int* __restrict__ idx = (b < 128) ? (ei + NE) : ei;
        ushort* __restrict__ outp = (b < 128) ? pcnt_dst : pcnt_src;
        for (int i = t; i < NB; i += 1024) h[i] = 0;
        __syncthreads();
        int base = p * EPB;
        for (int i = t; i < EPB; i += 1024) atomicAdd(&h[idx[base + i]], 1);
        __syncthreads();
        for (int i = t; i < NB; i += 1024) outp[p * NB + i] = (ushort)h[i];
        return;
    }
    // 32x32 transpose tiles, 1024 threads = one element each
    float* tld = (float*)h;  // [32][33]
    const float* W; ushort* Wt; int K, N, k0, n0;
    if (b < 320) {
        int bb = b - 256;
        W = W1; Wt = W1t; K = IN_DIM; N = HID_DIM;
        k0 = (bb & 3) * 32; n0 = (bb >> 2) * 32;
    } else {
        int bb = b - 320;
        W = W2; Wt = W2t; K = HID_DIM; N = OUT_DIM;
        k0 = (bb & 15) * 32; n0 = (bb >> 4) * 32;
    }
    int r = t >> 5, c = t & 31;
    tld[r * 33 + c] = W[(size_t)(k0 + r) * N + n0 + c];
    __syncthreads();
    Wt[(size_t)(n0 + r) * K + k0 + c] = f2b(tld[c * 33 + r]);
}

// Column reduce over partitions: deg_in, exclusive poff[p][v], norms.
__global__ __launch_bounds__(256) void colreduce_kernel(const ushort* __restrict__ pcnt_dst,
                                                        const ushort* __restrict__ pcnt_src,
                                                        int* __restrict__ poff,
                                                        int* __restrict__ deg_in,
                                                        float* __restrict__ norm_src,
                                                        float* __restrict__ norm_dst) {
    int v = blockIdx.x * 256 + threadIdx.x;  // 0..NB-1
    int s = 0;
#pragma unroll 4
    for (int p = 0; p < P_PART; p++) {
        int c = pcnt_dst[p * NB + v];
        poff[p * NB + v] = s;
        s += c;
    }
    deg_in[v] = s;
    int s2 = 0;
#pragma unroll 4
    for (int p = 0; p < P_PART; p++) s2 += pcnt_src[p * NB + v];
    if (v < NN) {
        norm_dst[v] = rsqrtf(fmaxf((float)s, 1.0f));
        norm_src[v] = rsqrtf(fmaxf((float)s2, 1.0f));
    }
}

// Fused: block 0 = single-block scan (deg -> row_off); blocks [1,314) = featconv.
__global__ __launch_bounds__(1024) void scanfeat_kernel(const int* __restrict__ deg,
                                                        int* __restrict__ row_off,
                                                        const float* __restrict__ feat,
                                                        const float* __restrict__ norm_src,
                                                        ushort* __restrict__ featb) {
    int b = blockIdx.x;
    int t = threadIdx.x;
    if (b == 0) {
        const int PER = NB / 1024;  // 10
        __shared__ int lds[1024];
        int base = t * PER;
        int local[PER];
        int s = 0;
#pragma unroll
        for (int i = 0; i < PER; i++) {
            int v = deg[base + i];
            local[i] = s;
            s += v;
        }
        lds[t] = s;
        __syncthreads();
        for (int off = 1; off < 1024; off <<= 1) {
            int x = (t >= off) ? lds[t - off] : 0;
            __syncthreads();
            lds[t] += x;
            __syncthreads();
        }
        int excl = lds[t] - s;
#pragma unroll
        for (int i = 0; i < PER; i++) {
            int idx = base + i;
            if (idx <= NN) row_off[idx] = excl + local[i];
        }
        return;
    }
    int i = (b - 1) * 1024 + t;  // float4 index
    if (i < NN * IN_DIM / 4) {
        float4 v = ((const float4*)feat)[i];
        float s = norm_src[i >> 5];
        ushort4 o;
        o.x = f2b(v.x * s); o.y = f2b(v.y * s); o.z = f2b(v.z * s); o.w = f2b(v.w * s);
        ((ushort4*)featb)[i] = o;
    }
}

// CSR fill with LDS-local cursors (no global atomics).
__global__ __launch_bounds__(1024) void fill_kernel(const int* __restrict__ src,
                                                    const int* __restrict__ dst,
                                                    const int* __restrict__ row_off,
                                                    const int* __restrict__ poff,
                                                    int* __restrict__ csr_src) {
    __shared__ int cur[NB];
    int p = blockIdx.x, t = threadIdx.x;
    for (int i = t; i < NB; i += 1024)
        cur[i] = ((i < NN) ? row_off[i] : 0) + poff[p * NB + i];
    __syncthreads();
    int base = p * EPB;
    for (int i = t; i < EPB; i += 1024) {
        int d = dst[base + i];
        int slot = atomicAdd(&cur[d], 1);
        csr_src[slot] = src[base + i];
    }
}

// One wave per node; 128 bf16 dims = 64 uints. Wave-uniform row base via readfirstlane.
__global__ __launch_bounds__(64) void agg1_kernel(const uint* __restrict__ fb,
                                                  const int* __restrict__ row_off,
                                                  const int* __restrict__ csr_src,
                                                  const float* __restrict__ norm_dst,
                                                  uint* __restrict__ aggb) {
    int node = blockIdx.x;
    uint lane = threadIdx.x;
    int beg = row_off[node], end = row_off[node + 1];
    f32x2 acc = {0.f, 0.f};
    int i = beg;
    for (; i + 8 <= end; i += 8) {
        const uint* rp[8];
#pragma unroll
        for (int j = 0; j < 8; j++)
            rp[j] = fb + (uint)__builtin_amdgcn_readfirstlane(csr_src[i + j]) * 64u;
        uint a[8];
#pragma unroll
        for (int j = 0; j < 8; j++) a[j] = rp[j][lane];
#pragma unroll
        for (int j = 0; j < 8; j++) {
            f32x2 v; v.x = blo(a[j]); v.y = bhi(a[j]);
            acc += v;
        }
    }
    for (; i < end; i++) {
        const uint* rp = fb + (uint)__builtin_amdgcn_readfirstlane(csr_src[i]) * 64u;
        uint a = rp[lane];
        f32x2 v; v.x = blo(a); v.y = bhi(a);
        acc += v;
    }
    float nd = norm_dst[node];
    aggb[node * 64 + lane] = (uint)f2b(acc.x * nd) | ((uint)f2b(acc.y * nd) << 16);
}

// Sliced 512-dim gather: grid (NN, 4); one wave = 128 dims (64 uints) of one node.
// Slice working set = 2.56 MB -> per-XCD L2 resident. Wave-uniform row base.
__global__ __launch_bounds__(64) void agg2_kernel(const uint* __restrict__ hb,
                                                  const int* __restrict__ row_off,
                                                  const int* __restrict__ csr_src,
                                                  const float* __restrict__ norm_dst,
                                                  uint* __restrict__ aggb) {
    int node = blockIdx.x;
    uint t = blockIdx.y * 64 + threadIdx.x;  // uint index 0..255
    int beg = row_off[node], end = row_off[node + 1];
    f32x2 acc = {0.f, 0.f};
    int i = beg;
    for (; i + 8 <= end; i += 8) {
        const uint* rp[8];
#pragma unroll
        for (int j = 0; j < 8; j++)
            rp[j] = hb + (uint)__builtin_amdgcn_readfirstlane(csr_src[i + j]) * 256u;
        uint a[8];
#pragma unroll
        for (int j = 0; j < 8; j++) a[j] = rp[j][t];
#pragma unroll
        for (int j = 0; j < 8; j++) {
            f32x2 v; v.x = blo(a[j]); v.y = bhi(a[j]);
            acc += v;
        }
    }
    for (; i < end; i++) {
        const uint* rp = hb + (uint)__builtin_amdgcn_readfirstlane(csr_src[i]) * 256u;
        uint a = rp[t];
        f32x2 v; v.x = blo(a); v.y = bhi(a);
        acc += v;
    }
    float nd = norm_dst[node];
    aggb[node * 256 + t] = (uint)f2b(acc.x * nd) | ((uint)f2b(acc.y * nd) << 16);
}

// bf16 MFMA GEMM: C[M][N] = A[M][K] @ Bt[N][K]^T (+bias).
// BM=128 BN=64 BK=32, 256 threads = 4 waves (2x2), fragment-ordered LDS via
// global_load_lds with pre-swizzled per-lane global source (linear LDS dest).
// A must be padded to BM multiple rows (OOB rows read garbage, masked at C-write).
// EPI 0: fp32 out = acc + bias.   EPI 1: bf16 out = relu(acc+bias) * scale[row].
template <int EPI>
__global__ __launch_bounds__(256) void gemm_bf16_kernel(const ushort* __restrict__ A,
                                                        const ushort* __restrict__ Bt,
                                                        const float* __restrict__ bias,
                                                        const float* __restrict__ scale,
                                                        void* __restrict__ Cout,
                                                        int M, int K, int N) {
    const int BM = 128;
    __shared__ __align__(16) ushort As[BM * 32];  // 512 16B chunks, fragment order
    __shared__ __align__(16) ushort Bs[64 * 32];  // 256 chunks
    int tid = threadIdx.x;
    int lane = tid & 63;
    int wid = tid >> 6;
    int bm = blockIdx.x * BM;
    int bn = blockIdx.y * 64;
    int wm = (wid & 1) * 64;
    int wn = (wid >> 1) * 32;

    // Pre-swizzled source coordinates: LDS chunk c holds (row, kq) with
    // row = ((c>>6)<<4)|(c&15), kq = (c>>4)&3.
    int cA0 = tid, cA1 = 256 + tid, cB = tid;
    int rowA0 = ((cA0 >> 6) << 4) | (cA0 & 15), kqA0 = (cA0 >> 4) & 3;
    int rowA1 = ((cA1 >> 6) << 4) | (cA1 & 15), kqA1 = (cA1 >> 4) & 3;
    int rowB = ((cB >> 6) << 4) | (cB & 15), kqB = (cB >> 4) & 3;
    const ushort* srcA0 = A + (size_t)(bm + rowA0) * K + kqA0 * 8;
    const ushort* srcA1 = A + (size_t)(bm + rowA1) * K + kqA1 * 8;
    const ushort* srcB = Bt + (size_t)(bn + rowB) * K + kqB * 8;
    ushort* ldsA0 = As + (wid * 64) * 8;
    ushort* ldsA1 = As + (256 + wid * 64) * 8;
    ushort* ldsB = Bs + (wid * 64) * 8;

    f32x4 acc[4][2] = {};

    for (int k0 = 0; k0 < K; k0 += 32) {
        __syncthreads();
        gl_lds16(srcA0 + k0, ldsA0);
        gl_lds16(srcA1 + k0, ldsA1);
        gl_lds16(srcB + k0, ldsB);
        __syncthreads();
        short8 af[4], bfr[2];
#pragma unroll
        for (int i = 0; i < 4; i++) {
            int j = (((wm >> 4) + i) << 6) + ((lane >> 4) << 4) + (lane & 15);
            af[i] = *(const short8*)(As + j * 8);
        }
#pragma unroll
        for (int i = 0; i < 2; i++) {
            int j = (((wn >> 4) + i) << 6) + ((lane >> 4) << 4) + (lane & 15);
            bfr[i] = *(const short8*)(Bs + j * 8);
        }
#pragma unroll
        for (int i = 0; i < 4; i++)
#pragma unroll
            for (int jn = 0; jn < 2; jn++)
                acc[i][jn] = __builtin_amdgcn_mfma_f32_16x16x32_bf16(af[i], bfr[jn], acc[i][jn], 0, 0, 0);
    }

#pragma unroll
    for (int i = 0; i < 4; i++) {
#pragma unroll
        for (int jn = 0; jn < 2; jn++) {
            int col = bn + wn + jn * 16 + (lane & 15);
            float bv = bias[col];
#pragma unroll
            for (int r = 0; r < 4; r++) {
                int gm = bm + wm + i * 16 + ((lane >> 4) << 2) + r;
                if (gm < M) {
                    float v = acc[i][jn][r] + bv;
                    if (EPI == 1) {
                        v = fmaxf(v, 0.f) * scale[gm];
                        ((ushort*)Cout)[(size_t)gm * N + col] = f2b(v);
                    } else {
                        ((float*)Cout)[(size_t)gm * N + col] = v;
                    }
                }
            }
        }
    }
}

extern "C" void kernel_launch(void* const* d_in, const int* in_sizes, int n_in,
                              void* d_out, int out_size, void* d_ws, size_t ws_size,
                              hipStream_t stream) {
    const float* feat = (const float*)d_in[0];
    const int* ei = (const int*)d_in[1];
    const float* W1 = (const float*)d_in[2];
    const float* b1 = (const float*)d_in[3];
    const float* W2 = (const float*)d_in[4];
    const float* b2 = (const float*)d_in[5];
    float* out = (float*)d_out;

    const int* src = ei;
    const int* dst = ei + NE;
    const int NNP = 10112;  // NN padded to BM=128 multiple (A-panel OOB safety)

    char* ws = (char*)d_ws;
    size_t off = 0;
    auto alloc = [&](size_t bytes) -> void* {
        void* p = ws + off;
        off += (bytes + 255) & ~(size_t)255;
        return p;
    };
    // ---- fixed region ----
    int* row_off = (int*)alloc((NN + 16) * sizeof(int));
    int* deg_in = (int*)alloc(NB * sizeof(int));
    float* norm_src = (float*)alloc(NN * sizeof(float));
    float* norm_dst = (float*)alloc(NN * sizeof(float));
    int* csr_src = (int*)alloc(NE * sizeof(int));
    ushort* featb = (ushort*)alloc((size_t)NN * IN_DIM * 2);
    ushort* W1t = (ushort*)alloc((size_t)HID_DIM * IN_DIM * 2);
    ushort* W2t = (ushort*)alloc((size_t)OUT_DIM * HID_DIM * 2);
    // ---- union region: prep {pcnt_dst, pcnt_src, poff} overlaps main {agg1b, hb, agg2b} ----
    size_t union_base = off;
    ushort* pcnt_dst = (ushort*)alloc((size_t)P_PART * NB * sizeof(ushort));  // 2.62 MB
    ushort* pcnt_src = (ushort*)alloc((size_t)P_PART * NB * sizeof(ushort));  // 2.62 MB
    int* poff = (int*)alloc((size_t)P_PART * NB * sizeof(int));               // 5.24 MB
    off = union_base;
    ushort* agg1b = (ushort*)alloc((size_t)NNP * IN_DIM * 2);   // padded A-panel
    ushort* hb = (ushort*)alloc((size_t)NN * HID_DIM * 2);      // 10.24 MB
    ushort* agg2b = (ushort*)alloc((size_t)NNP * HID_DIM * 2);  // padded A-panel

    // ---- graph prep (no global atomics) + W transposes ----
    histw_kernel<<<576, 1024, 0, stream>>>(ei, pcnt_dst, pcnt_src, W1, W1t, W2, W2t);
    colreduce_kernel<<<NB / 256, 256, 0, stream>>>(pcnt_dst, pcnt_src, poff, deg_in, norm_src, norm_dst);
    scanfeat_kernel<<<314, 1024, 0, stream>>>(deg_in, row_off, feat, norm_src, featb);
    fill_kernel<<<P_PART, 1024, 0, stream>>>(src, dst, row_off, poff, csr_src);

    // ---- layer 1 ----
    agg1_kernel<<<NN, 64, 0, stream>>>((const uint*)featb, row_off, csr_src, norm_dst, (uint*)agg1b);
    {
        dim3 grid(NNP / 128, HID_DIM / 64);
        gemm_bf16_kernel<1><<<grid, 256, 0, stream>>>(agg1b, W1t, b1, norm_src, hb, NN, IN_DIM, HID_DIM);
    }
    // ---- layer 2 ----
    {
        dim3 grid(NN, 4);
        agg2_kernel<<<grid, 64, 0, stream>>>((const uint*)hb, row_off, csr_src, norm_dst, (uint*)agg2b);
    }
    {
        dim3 grid(NNP / 128, OUT_DIM / 64);
        gemm_bf16_kernel<0><<<grid, 256, 0, stream>>>(agg2b, W2t, b2, nullptr, out, NN, HID_DIM, OUT_DIM);
    }
}